// Round 8
// baseline (82.898 us; speedup 1.0000x reference)
//
#include <hip/hip_runtime.h>

typedef float fx4 __attribute__((ext_vector_type(4)));

// Fast 8-point DCT-II (unnormalized: o[u] = sum_x a[x]*cos((2x+1)u*pi/16)),
// even/odd factored. All coefficients literal.
__device__ __forceinline__ void dct8(const float a[8], float o[8]) {
    const float s0 = a[0] + a[7], s1 = a[1] + a[6], s2 = a[2] + a[5], s3 = a[3] + a[4];
    const float d0 = a[0] - a[7], d1 = a[1] - a[6], d2 = a[2] - a[5], d3 = a[3] - a[4];
    const float ss0 = s0 + s3, ss1 = s1 + s2;
    const float ds0 = s0 - s3, ds1 = s1 - s2;
    o[0] = ss0 + ss1;
    o[4] = 0.70710678f * (ss0 - ss1);
    o[2] = fmaf(0.92387953f, ds0,  0.38268343f * ds1);
    o[6] = fmaf(0.38268343f, ds0, -0.92387953f * ds1);
    o[1] = fmaf(0.98078528f, d0, fmaf( 0.83146961f, d1, fmaf( 0.55557023f, d2,  0.19509032f * d3)));
    o[3] = fmaf(0.83146961f, d0, fmaf(-0.19509032f, d1, fmaf(-0.98078528f, d2, -0.55557023f * d3)));
    o[5] = fmaf(0.55557023f, d0, fmaf(-0.98078528f, d1, fmaf( 0.19509032f, d2,  0.83146961f * d3)));
    o[7] = fmaf(0.19509032f, d0, fmaf(-0.55557023f, d1, fmaf( 0.83146961f, d2, -0.98078528f * d3)));
}

// Persistent-grid software-pipelined variant of R7:
//   prologue load -> { prefetch next iter's rows, process current, store } x12
// The prefetch decouples the HBM read stream from the per-iteration dependent
// chain (LDS transpose x2 + two DCTs), keeping reads outstanding like a copy
// kernel. All cross-lane exchange stays within the wave's 8-lane groups in
// one LDS buffer -> NO barriers. Loop trip count is uniform (gstride divides
// the row count exactly), so no divergence.
__global__ __launch_bounds__(256) void dct8x8_kernel(const float* __restrict__ in,
                                                     float* __restrict__ out,
                                                     int nrows, int niter) {
    __shared__ alignas(16) float lds1[32 * 68];

    const int l     = threadIdx.x & 7;
    const int base  = (threadIdx.x >> 3) * 68;
    const int cbase = base + (l & 4) * 8 + (l & 3);
    const int gstride = gridDim.x * 256;

    const fx4* __restrict__ p = reinterpret_cast<const fx4*>(in);
    fx4* __restrict__ q = reinterpret_cast<fx4*>(out);

    size_t idx = (size_t)blockIdx.x * 256 + threadIdx.x;

    // ---- prologue: load first tile ----
    fx4 v0 = __builtin_nontemporal_load(p + idx * 2);
    fx4 v1 = __builtin_nontemporal_load(p + idx * 2 + 1);

    for (int it = 0; it < niter; ++it) {
        // ---- prefetch next tile (full body of work to cover its latency) ----
        const size_t nidx = idx + gstride;
        fx4 n0, n1;
        if (it + 1 < niter) {
            n0 = __builtin_nontemporal_load(p + nidx * 2);
            n1 = __builtin_nontemporal_load(p + nidx * 2 + 1);
        }

        // ---- row pass on current tile ----
        float a[8] = { v0[0], v0[1], v0[2], v0[3], v1[0], v1[1], v1[2], v1[3] };
        float r[8];
        dct8(a, r);
        r[0] -= 1024.0f;   // -128 input shift only affects the row DC (8*128)

        // ---- transpose #1: write row (2x b128), read column l (8x b32) ----
        fx4 w0 = { r[0], r[1], r[2], r[3] };
        fx4 w1 = { r[4], r[5], r[6], r[7] };
        *reinterpret_cast<fx4*>(&lds1[base + l * 4])      = w0;
        *reinterpret_cast<fx4*>(&lds1[base + 32 + l * 4]) = w1;

        float t[8];
#pragma unroll
        for (int y = 0; y < 8; ++y) t[y] = lds1[cbase + y * 4];

        // ---- column pass -> output column l ----
        float o[8];
        dct8(t, o);

        // ---- scale[u][l] = (0.5*alpha_u)(0.5*alpha_l) ----
        const float sl = (l == 0) ? 0.35355339059f : 0.5f;
#pragma unroll
        for (int u = 0; u < 8; ++u) o[u] *= sl * ((u == 0) ? 0.35355339059f : 0.5f);

        // ---- transpose #2 (same buffer): scatter column, read row l ----
#pragma unroll
        for (int u = 0; u < 8; ++u) lds1[cbase + u * 4] = o[u];

        fx4 q0 = *reinterpret_cast<const fx4*>(&lds1[base + l * 4]);
        fx4 q1 = *reinterpret_cast<const fx4*>(&lds1[base + 32 + l * 4]);

        // ---- coalesced regular store ----
        q[idx * 2]     = q0;
        q[idx * 2 + 1] = q1;

        idx = nidx;
        v0 = n0;
        v1 = n1;
    }
}

extern "C" void kernel_launch(void* const* d_in, const int* in_sizes, int n_in,
                              void* d_out, int out_size, void* d_ws, size_t ws_size,
                              hipStream_t stream) {
    const float* in = (const float*)d_in[0];
    float* out = (float*)d_out;
    const int n = in_sizes[0];          // 64*3*4096*64 = 50,331,648 floats
    const int nrows = n / 8;            // 6,291,456 block-rows (one lane each)
    const int grid = 2048;              // 2048*256 = 524,288 threads
    const int niter = nrows / (grid * 256);   // exactly 12, uniform
    hipLaunchKernelGGL(dct8x8_kernel, dim3(grid), dim3(256), 0, stream,
                       in, out, nrows, niter);
}

// Round 9
// 78.560 us; speedup vs baseline: 1.0552x; 1.0552x over previous
//
#include <hip/hip_runtime.h>

typedef float fx4 __attribute__((ext_vector_type(4)));

// Fast 8-point DCT-II (unnormalized: o[u] = sum_x a[x]*cos((2x+1)u*pi/16)),
// even/odd factored. All coefficients literal.
__device__ __forceinline__ void dct8(const float a[8], float o[8]) {
    const float s0 = a[0] + a[7], s1 = a[1] + a[6], s2 = a[2] + a[5], s3 = a[3] + a[4];
    const float d0 = a[0] - a[7], d1 = a[1] - a[6], d2 = a[2] - a[5], d3 = a[3] - a[4];
    const float ss0 = s0 + s3, ss1 = s1 + s2;
    const float ds0 = s0 - s3, ds1 = s1 - s2;
    o[0] = ss0 + ss1;
    o[4] = 0.70710678f * (ss0 - ss1);
    o[2] = fmaf(0.92387953f, ds0,  0.38268343f * ds1);
    o[6] = fmaf(0.38268343f, ds0, -0.92387953f * ds1);
    o[1] = fmaf(0.98078528f, d0, fmaf( 0.83146961f, d1, fmaf( 0.55557023f, d2,  0.19509032f * d3)));
    o[3] = fmaf(0.83146961f, d0, fmaf(-0.19509032f, d1, fmaf(-0.98078528f, d2, -0.55557023f * d3)));
    o[5] = fmaf(0.55557023f, d0, fmaf(-0.98078528f, d1, fmaf( 0.19509032f, d2,  0.83146961f * d3)));
    o[7] = fmaf(0.19509032f, d0, fmaf(-0.55557023f, d1, fmaf( 0.83146961f, d2, -0.98078528f * d3)));
}

// R7 structure, but 4 tiles per thread with ALL eight load instructions issued
// unconditionally up front: 8 KB of reads in flight per wave (4x R7) to test
// whether read-side MLP is what separates us (5.3 TB/s) from copy (6.3 TB/s).
// Tiles are spaced CHUNK rows apart; within a chunk the access is identical
// to R7 (fully lane-contiguous fx4). Exact division -> no guards anywhere.
// All cross-lane exchange stays within the wave's 8-lane groups in one LDS
// buffer -> NO barriers; the 4 bodies reuse it serially (per-wave DS order).
__global__ __launch_bounds__(256) void dct8x8_kernel(const float* __restrict__ in,
                                                     float* __restrict__ out,
                                                     size_t chunk) {
    __shared__ alignas(16) float lds1[32 * 68];

    const int l     = threadIdx.x & 7;
    const int base  = (threadIdx.x >> 3) * 68;
    const int cbase = base + (l & 4) * 8 + (l & 3);

    const fx4* __restrict__ p = reinterpret_cast<const fx4*>(in);
    fx4* __restrict__ q = reinterpret_cast<fx4*>(out);

    const size_t idx0 = (size_t)blockIdx.x * 256 + threadIdx.x;

    // ---- issue all 8 loads up front (independent, unconditional) ----
    fx4 v[4][2];
#pragma unroll
    for (int k = 0; k < 4; ++k) {
        const size_t idx = idx0 + (size_t)k * chunk;
        v[k][0] = __builtin_nontemporal_load(p + idx * 2);
        v[k][1] = __builtin_nontemporal_load(p + idx * 2 + 1);
    }

    // ---- process the 4 tiles serially through the shared transpose buffer ----
#pragma unroll
    for (int k = 0; k < 4; ++k) {
        float a[8] = { v[k][0][0], v[k][0][1], v[k][0][2], v[k][0][3],
                       v[k][1][0], v[k][1][1], v[k][1][2], v[k][1][3] };

        float r[8];
        dct8(a, r);
        r[0] -= 1024.0f;   // -128 input shift only affects the row DC (8*128)

        // transpose #1: write own row (2x b128), read column l (8x b32)
        fx4 w0 = { r[0], r[1], r[2], r[3] };
        fx4 w1 = { r[4], r[5], r[6], r[7] };
        *reinterpret_cast<fx4*>(&lds1[base + l * 4])      = w0;
        *reinterpret_cast<fx4*>(&lds1[base + 32 + l * 4]) = w1;

        float t[8];
#pragma unroll
        for (int y = 0; y < 8; ++y) t[y] = lds1[cbase + y * 4];

        float o[8];
        dct8(t, o);

        const float sl = (l == 0) ? 0.35355339059f : 0.5f;
#pragma unroll
        for (int u = 0; u < 8; ++u) o[u] *= sl * ((u == 0) ? 0.35355339059f : 0.5f);

        // transpose #2 (same buffer): scatter column, read own row
#pragma unroll
        for (int u = 0; u < 8; ++u) lds1[cbase + u * 4] = o[u];

        fx4 q0 = *reinterpret_cast<const fx4*>(&lds1[base + l * 4]);
        fx4 q1 = *reinterpret_cast<const fx4*>(&lds1[base + 32 + l * 4]);

        const size_t idx = idx0 + (size_t)k * chunk;
        q[idx * 2]     = q0;
        q[idx * 2 + 1] = q1;
    }
}

extern "C" void kernel_launch(void* const* d_in, const int* in_sizes, int n_in,
                              void* d_out, int out_size, void* d_ws, size_t ws_size,
                              hipStream_t stream) {
    const float* in = (const float*)d_in[0];
    float* out = (float*)d_out;
    const int n = in_sizes[0];            // 64*3*4096*64 = 50,331,648 floats
    const int nrows = n / 8;              // 6,291,456 block-rows
    const int grid = nrows / (256 * 4);   // 6144 blocks, divides exactly
    const size_t chunk = (size_t)grid * 256;  // 1,572,864 rows between tiles
    hipLaunchKernelGGL(dct8x8_kernel, dim3(grid), dim3(256), 0, stream,
                       in, out, chunk);
}

// Round 10
// 75.972 us; speedup vs baseline: 1.0912x; 1.0341x over previous
//
#include <hip/hip_runtime.h>

typedef float fx4 __attribute__((ext_vector_type(4)));

// Fast 8-point DCT-II (unnormalized: o[u] = sum_x a[x]*cos((2x+1)u*pi/16)),
// even/odd factored. All coefficients literal.
__device__ __forceinline__ void dct8(const float a[8], float o[8]) {
    const float s0 = a[0] + a[7], s1 = a[1] + a[6], s2 = a[2] + a[5], s3 = a[3] + a[4];
    const float d0 = a[0] - a[7], d1 = a[1] - a[6], d2 = a[2] - a[5], d3 = a[3] - a[4];
    const float ss0 = s0 + s3, ss1 = s1 + s2;
    const float ds0 = s0 - s3, ds1 = s1 - s2;
    o[0] = ss0 + ss1;
    o[4] = 0.70710678f * (ss0 - ss1);
    o[2] = fmaf(0.92387953f, ds0,  0.38268343f * ds1);
    o[6] = fmaf(0.38268343f, ds0, -0.92387953f * ds1);
    o[1] = fmaf(0.98078528f, d0, fmaf( 0.83146961f, d1, fmaf( 0.55557023f, d2,  0.19509032f * d3)));
    o[3] = fmaf(0.83146961f, d0, fmaf(-0.19509032f, d1, fmaf(-0.98078528f, d2, -0.55557023f * d3)));
    o[5] = fmaf(0.55557023f, d0, fmaf(-0.98078528f, d1, fmaf( 0.19509032f, d2,  0.83146961f * d3)));
    o[7] = fmaf(0.19509032f, d0, fmaf(-0.55557023f, d1, fmaf( 0.83146961f, d2, -0.98078528f * d3)));
}

// Best-measured structure (R7, 75.8 us = 5.3 TB/s effective on 402 MB/call):
// 8 lanes per 8x8 block, lane l owns row l end-to-end. Two LDS transposes in
// ONE shared buffer; all exchange within the wave's own 8-lane groups -> NO
// barriers. Layout per group (stride 68 words): M[row][v] at
//   base + (v&4)*8 + row*4 + (v&3)
// -> row write = 2x ds_write_b128 (lane-consecutive 16B), column read =
//    8x ds_read_b32 at exactly 2 lanes/bank (free). Global I/O is fully
//    lane-contiguous fx4 both directions; nt-loads (small but nonnegative).
__global__ __launch_bounds__(256) void dct8x8_kernel(const float* __restrict__ in,
                                                     float* __restrict__ out) {
    __shared__ alignas(16) float lds1[32 * 68];

    const int tid  = blockIdx.x * 256 + threadIdx.x;   // grid divides exactly
    const int l    = threadIdx.x & 7;
    const int base = (threadIdx.x >> 3) * 68;
    const int cbase = base + (l & 4) * 8 + (l & 3);

    // ---- nontemporal load of row l (32 B, fully coalesced) ----
    const fx4* p = reinterpret_cast<const fx4*>(in) + (size_t)tid * 2;
    fx4 v0 = __builtin_nontemporal_load(p);
    fx4 v1 = __builtin_nontemporal_load(p + 1);
    float a[8] = { v0[0], v0[1], v0[2], v0[3], v1[0], v1[1], v1[2], v1[3] };

    // ---- row pass ----
    float r[8];
    dct8(a, r);
    r[0] -= 1024.0f;   // global -128 shift only affects the row DC (8*128)

    // ---- transpose #1: write row (2x b128), read column l (8x b32) ----
    fx4 w0 = { r[0], r[1], r[2], r[3] };
    fx4 w1 = { r[4], r[5], r[6], r[7] };
    *reinterpret_cast<fx4*>(&lds1[base + l * 4])      = w0;
    *reinterpret_cast<fx4*>(&lds1[base + 32 + l * 4]) = w1;

    float t[8];
#pragma unroll
    for (int y = 0; y < 8; ++y) t[y] = lds1[cbase + y * 4];

    // ---- column pass -> output column l ----
    float o[8];
    dct8(t, o);

    // ---- scale[u][l] = (0.5*alpha_u)(0.5*alpha_l) ----
    const float sl = (l == 0) ? 0.35355339059f : 0.5f;
#pragma unroll
    for (int u = 0; u < 8; ++u) o[u] *= sl * ((u == 0) ? 0.35355339059f : 0.5f);

    // ---- transpose #2 (same buffer): scatter column (8x b32), read row (2x b128) ----
#pragma unroll
    for (int u = 0; u < 8; ++u) lds1[cbase + u * 4] = o[u];

    fx4 q0 = *reinterpret_cast<const fx4*>(&lds1[base + l * 4]);
    fx4 q1 = *reinterpret_cast<const fx4*>(&lds1[base + 32 + l * 4]);

    // ---- coalesced regular store ----
    fx4* qp = reinterpret_cast<fx4*>(out) + (size_t)tid * 2;
    qp[0] = q0;
    qp[1] = q1;
}

extern "C" void kernel_launch(void* const* d_in, const int* in_sizes, int n_in,
                              void* d_out, int out_size, void* d_ws, size_t ws_size,
                              hipStream_t stream) {
    const float* in = (const float*)d_in[0];
    float* out = (float*)d_out;
    const int n = in_sizes[0];          // 64*3*4096*64 = 50,331,648 floats
    const int nthreads = n / 8;         // one lane per block-row
    const int grid = (nthreads + 255) / 256;
    hipLaunchKernelGGL(dct8x8_kernel, dim3(grid), dim3(256), 0, stream,
                       in, out);
}